// Round 12
// baseline (224.351 us; speedup 1.0000x reference)
//
#include <hip/hip_runtime.h>
#include <hip/hip_bf16.h>
#include <stdint.h>

#define B_ROWS 2048
#define SEQ 512
#define VOC 30000
#define DMODEL 768
#define K1 1.2f
#define BPAR 0.75f
#define NT 192   // 3 waves; each thread owns one ushort4 (4 bf16) chunk of 768 dims
#define PF 8     // prefetch depth — R7-proven operating point

// ---------------- Kernel 1: transpose W [768][30000] f32 -> Wb [30000][768] bf16 -------
// 64j x 256t tiles. Reads: float4 (1KB/wave-instr). Writes: full 128B lines. (R11: ~25us)
__launch_bounds__(256)
__global__ void transpose_W256(const float* __restrict__ W, __hip_bfloat16* __restrict__ Wb) {
    __shared__ __hip_bfloat16 tile[64][258];
    int tBase = blockIdx.x * 256;
    int jBase = blockIdx.y * 64;
    int tx = threadIdx.x;   // 0..63
    int ty = threadIdx.y;   // 0..3

#pragma unroll
    for (int jj = 0; jj < 16; jj++) {
        int j = jBase + jj * 4 + ty;
        int t = tBase + tx * 4;
        if (t < VOC) {
            float4 v = *(const float4*)(W + (size_t)j * VOC + t);
            int c = tx * 4;
            tile[jj * 4 + ty][c]     = __float2bfloat16(v.x);
            tile[jj * 4 + ty][c + 1] = __float2bfloat16(v.y);
            tile[jj * 4 + ty][c + 2] = __float2bfloat16(v.z);
            tile[jj * 4 + ty][c + 3] = __float2bfloat16(v.w);
        }
    }
    __syncthreads();

#pragma unroll
    for (int i = 0; i < 64; i++) {
        int trow = i * 4 + ty;
        int t = tBase + trow;
        if (t < VOC) {
            Wb[(size_t)t * DMODEL + jBase + tx] = tile[tx][trow];
        }
    }
}

__device__ __forceinline__ float b2f(unsigned short h) {
    union { uint32_t u; float f; } v; v.u = ((uint32_t)h) << 16; return v.f;
}

// ---------------- Kernel 2: per-doc-half BM25 gather (partial accumulate) -------------
// Two blocks per doc (grid 4096). Both run identical compact+sort+weight phases (tf
// needs the full doc); half h then gathers sorted positions 2i+h via the byte-identical
// R7 PF=8 loop over contiguous per-half lists. Both halves sweep ascending in phase.
__launch_bounds__(NT, 6)
__global__ void bm25_half(const int* __restrict__ ids, const int* __restrict__ mask,
                          const __hip_bfloat16* __restrict__ Wb,
                          float* __restrict__ part) {
    __shared__ int   stoks[SEQ];
    __shared__ float wts[SEQ];
    __shared__ int   hstoks[SEQ / 2];
    __shared__ float hwts[SEQ / 2];
    __shared__ int   nv;

    int b    = blockIdx.x & (B_ROWS - 1);   // doc
    int half = blockIdx.x >> 11;            // 0/1
    int tid = threadIdx.x;

    if (tid == 0) nv = 0;
    __syncthreads();

    // compact valid tokens (order irrelevant; sort follows)
    for (int i = tid; i < SEQ; i += NT) {
        int id = ids[(size_t)b * SEQ + i];
        int m  = mask[(size_t)b * SEQ + i];
        if (m == 1 && id > 100 && id < VOC) {
            stoks[atomicAdd(&nv, 1)] = id;
        }
    }
    __syncthreads();
    int n = nv;  // == doc_len (positions with multiplicity)

    // pad to 512 with +inf keys
    for (int i = n + tid; i < SEQ; i += NT) stoks[i] = 0x7fffffff;

    // bitonic sort of 512 ints (first barrier inside loop covers padding writes)
    for (int k = 2; k <= SEQ; k <<= 1) {
        for (int j = k >> 1; j > 0; j >>= 1) {
            __syncthreads();
            for (int i = tid; i < SEQ; i += NT) {
                int ixj = i ^ j;
                if (ixj > i) {
                    int a = stoks[i], c = stoks[ixj];
                    if ((a > c) == ((i & k) == 0)) { stoks[i] = c; stoks[ixj] = a; }
                }
            }
        }
    }
    __syncthreads();

    // per-position weight: score(tf)/tf = (K1+1)/(tf + K1*len_norm); tf via sorted runs
    float kln = K1 * fmaxf(1.0f + BPAR * ((float)n / 100.0f - 1.0f), 0.5f);
    for (int i = tid; i < n; i += NT) {
        int t = stoks[i];
        int lo = i; while (lo > 0 && stoks[lo - 1] == t) lo--;
        int hi = i; while (hi < n - 1 && stoks[hi + 1] == t) hi++;
        wts[i] = (K1 + 1.0f) / ((float)(hi - lo + 1) + kln);
    }
    __syncthreads();

    // compact this half's positions (2i+half) into contiguous lists (keeps R7 loop shape)
    int m = (n + 1 - half) >> 1;
    for (int i = tid; i < m; i += NT) {
        int p = (i << 1) | half;
        hstoks[i] = stoks[p];
        hwts[i]   = wts[p];
    }
    __syncthreads();

    // gather-accumulate in ascending vocab order; thread owns bf16x4 chunk `tid`
    const ushort4* __restrict__ Wb4 = (const ushort4*)Wb;   // row stride DMODEL/4 = 192
    float4 acc = make_float4(0.f, 0.f, 0.f, 0.f);
    int p = 0;
    for (; p + PF <= m; p += PF) {
        ushort4 r[PF];
        float   w[PF];
#pragma unroll
        for (int q = 0; q < PF; q++) {
            r[q] = Wb4[(size_t)hstoks[p + q] * (DMODEL / 4) + tid];
            w[q] = hwts[p + q];
        }
#pragma unroll
        for (int q = 0; q < PF; q++) {
            acc.x = fmaf(w[q], b2f(r[q].x), acc.x);
            acc.y = fmaf(w[q], b2f(r[q].y), acc.y);
            acc.z = fmaf(w[q], b2f(r[q].z), acc.z);
            acc.w = fmaf(w[q], b2f(r[q].w), acc.w);
        }
    }
    for (; p < m; p++) {
        float w = hwts[p];
        ushort4 r = Wb4[(size_t)hstoks[p] * (DMODEL / 4) + tid];
        acc.x = fmaf(w, b2f(r.x), acc.x);
        acc.y = fmaf(w, b2f(r.y), acc.y);
        acc.z = fmaf(w, b2f(r.z), acc.z);
        acc.w = fmaf(w, b2f(r.w), acc.w);
    }

    // store partial (no norm yet)
    ((float4*)(part + ((size_t)half * B_ROWS + b) * DMODEL))[tid] = acc;
}

// ---------------- Kernel 3: combine halves + normalize --------------------------------
__launch_bounds__(NT)
__global__ void bm25_combine(const float* __restrict__ part, float* __restrict__ out) {
    __shared__ float wred[3];
    int b = blockIdx.x;
    int tid = threadIdx.x;

    float4 a0 = ((const float4*)(part + (size_t)b * DMODEL))[tid];
    float4 a1 = ((const float4*)(part + ((size_t)B_ROWS + b) * DMODEL))[tid];
    float4 acc;
    acc.x = a0.x + a1.x; acc.y = a0.y + a1.y; acc.z = a0.z + a1.z; acc.w = a0.w + a1.w;

    float ss = acc.x * acc.x + acc.y * acc.y + acc.z * acc.z + acc.w * acc.w;
#pragma unroll
    for (int off = 32; off > 0; off >>= 1) ss += __shfl_down(ss, off);
    if ((tid & 63) == 0) wred[tid >> 6] = ss;
    __syncthreads();
    float inv = rsqrtf(fmaxf(wred[0] + wred[1] + wred[2], 1e-30f));

    float4 o;
    o.x = acc.x * inv; o.y = acc.y * inv; o.z = acc.z * inv; o.w = acc.w * inv;
    ((float4*)(out + (size_t)b * DMODEL))[tid] = o;
}

extern "C" void kernel_launch(void* const* d_in, const int* in_sizes, int n_in,
                              void* d_out, int out_size, void* d_ws, size_t ws_size,
                              hipStream_t stream) {
    const int*   ids  = (const int*)d_in[0];
    const int*   mask = (const int*)d_in[1];
    const float* W    = (const float*)d_in[2];
    float* out = (float*)d_out;

    __hip_bfloat16* Wb = (__hip_bfloat16*)d_ws;            // 30000*768*2 = 46,080,000 B
    float* part = (float*)((char*)d_ws + (size_t)VOC * DMODEL * sizeof(__hip_bfloat16));
    // part: 2 * 2048 * 768 * 4 = 12,582,912 B

    dim3 tgrid((VOC + 255) / 256, DMODEL / 64);
    dim3 tblock(64, 4);
    transpose_W256<<<tgrid, tblock, 0, stream>>>(W, Wb);

    bm25_half<<<B_ROWS * 2, NT, 0, stream>>>(ids, mask, Wb, part);

    bm25_combine<<<B_ROWS, NT, 0, stream>>>(part, out);
}

// Round 13
// 160.275 us; speedup vs baseline: 1.3998x; 1.3998x over previous
//
#include <hip/hip_runtime.h>
#include <hip/hip_bf16.h>
#include <stdint.h>

#define B_ROWS 2048
#define SEQ 512
#define VOC 30000
#define DMODEL 768
#define K1 1.2f
#define BPAR 0.75f
#define NT 192    // gather: 3 waves; each thread owns one ushort4 (4 bf16) chunk
#define PF 8      // prefetch depth — R7-proven operating point
#define TGX 118   // ceil(VOC/256) transpose tiles in t
#define TGY 12    // DMODEL/64 transpose tiles in j
#define TTILES (TGX * TGY)   // 1416

// ---------------- Kernel 1: fused W-transpose + doc prep (role-split by blockIdx) ------
// Blocks [0, TTILES): transpose W [768][30000] f32 -> Wb [30000][768] bf16
//   (64j x 256t tiles, float4 reads, full-128B-line writes — R11-proven, ~25us).
// Blocks [TTILES, TTILES+B_ROWS): per-doc compact + bitonic sort + BM25 weights
//   (R7-proven phases, 256 threads), written to global lists; tokens premultiplied by
//   DMODEL/4 so the gather's addressing is a single add. Prep VALU work (~15us) hides
//   under the transpose's memory-bound phase -> overlap that stream order forbids.
__launch_bounds__(256)
__global__ void prep_all(const float* __restrict__ W, __hip_bfloat16* __restrict__ Wb,
                         const int* __restrict__ ids, const int* __restrict__ mask,
                         int* __restrict__ stoks_g, float* __restrict__ wts_g,
                         int* __restrict__ n_g) {
    __shared__ ushort smem[64 * 258];   // 33,024 B: transpose tile OR prep scratch
    int bid = blockIdx.x;
    int tid = threadIdx.x;

    if (bid < TTILES) {
        // ---- transpose role ----
        ushort (*tile)[258] = (ushort(*)[258])smem;
        int bx = bid % TGX, by = bid / TGX;
        int tBase = bx * 256;
        int jBase = by * 64;
        int tx = tid & 63;    // lane
        int ty = tid >> 6;    // wave

#pragma unroll
        for (int jj = 0; jj < 16; jj++) {
            int j = jBase + jj * 4 + ty;
            int t = tBase + tx * 4;
            if (t < VOC) {   // VOC % 4 == 0 -> full float4 in range
                float4 v = *(const float4*)(W + (size_t)j * VOC + t);
                int c = tx * 4;
                tile[jj * 4 + ty][c]     = __bfloat16_as_ushort(__float2bfloat16(v.x));
                tile[jj * 4 + ty][c + 1] = __bfloat16_as_ushort(__float2bfloat16(v.y));
                tile[jj * 4 + ty][c + 2] = __bfloat16_as_ushort(__float2bfloat16(v.z));
                tile[jj * 4 + ty][c + 3] = __bfloat16_as_ushort(__float2bfloat16(v.w));
            }
        }
        __syncthreads();

#pragma unroll
        for (int i = 0; i < 64; i++) {
            int trow = i * 4 + ty;
            int t = tBase + trow;
            if (t < VOC) {
                ((ushort*)Wb)[(size_t)t * DMODEL + jBase + tx] = tile[tx][trow];
            }
        }
    } else {
        // ---- doc-prep role ----
        int b = bid - TTILES;
        int*   stoks = (int*)smem;                       // 512 ints  @ byte 0
        float* wts   = (float*)((char*)smem + 2048);     // 512 f32   @ byte 2048
        int*   nvp   = (int*)((char*)smem + 4096);

        if (tid == 0) *nvp = 0;
        __syncthreads();

        // compact valid tokens (order irrelevant; sort follows)
        for (int i = tid; i < SEQ; i += 256) {
            int id = ids[(size_t)b * SEQ + i];
            int m  = mask[(size_t)b * SEQ + i];
            if (m == 1 && id > 100 && id < VOC) {
                stoks[atomicAdd(nvp, 1)] = id;
            }
        }
        __syncthreads();
        int n = *nvp;   // == doc_len (positions with multiplicity)

        // pad to 512 with +inf keys
        for (int i = n + tid; i < SEQ; i += 256) stoks[i] = 0x7fffffff;

        // bitonic sort of 512 ints
        for (int k = 2; k <= SEQ; k <<= 1) {
            for (int j = k >> 1; j > 0; j >>= 1) {
                __syncthreads();
                for (int i = tid; i < SEQ; i += 256) {
                    int ixj = i ^ j;
                    if (ixj > i) {
                        int a = stoks[i], c = stoks[ixj];
                        if ((a > c) == ((i & k) == 0)) { stoks[i] = c; stoks[ixj] = a; }
                    }
                }
            }
        }
        __syncthreads();

        // weight: (K1+1)/(tf + K1*len_norm), tf via sorted runs
        float kln = K1 * fmaxf(1.0f + BPAR * ((float)n / 100.0f - 1.0f), 0.5f);
        for (int i = tid; i < n; i += 256) {
            int t = stoks[i];
            int lo = i; while (lo > 0 && stoks[lo - 1] == t) lo--;
            int hi = i; while (hi < n - 1 && stoks[hi + 1] == t) hi++;
            wts[i] = (K1 + 1.0f) / ((float)(hi - lo + 1) + kln);
        }
        __syncthreads();

        // store sorted lists; token premultiplied to ushort4-row offset (tok * DMODEL/4)
        for (int i = tid; i < n; i += 256) {
            stoks_g[(size_t)b * SEQ + i] = stoks[i] * (DMODEL / 4);
            wts_g[(size_t)b * SEQ + i]   = wts[i];
        }
        if (tid == 0) n_g[b] = n;
    }
}

__device__ __forceinline__ float b2f(unsigned short h) {
    union { uint32_t u; float f; } v; v.u = ((uint32_t)h) << 16; return v.f;
}

// ---------------- Kernel 2: pure gather + normalize ------------------------------------
// Loads presorted lists (coalesced, ~8KB/block), then the R7-proven PF=8 loop —
// byte-identical structure; stoks now holds premultiplied row offsets (one add per
// address). No sort barriers -> all 2048 blocks enter the ascending sweep in phase.
__launch_bounds__(NT, 6)
__global__ void bm25_gather(const int* __restrict__ stoks_g, const float* __restrict__ wts_g,
                            const int* __restrict__ n_g,
                            const __hip_bfloat16* __restrict__ Wb,
                            float* __restrict__ out) {
    __shared__ int   stoks[SEQ];
    __shared__ float wts[SEQ];
    __shared__ float wred[3];

    int b = blockIdx.x;
    int tid = threadIdx.x;
    int n = n_g[b];   // block-uniform

    for (int i = tid; i < n; i += NT) {
        stoks[i] = stoks_g[(size_t)b * SEQ + i];
        wts[i]   = wts_g[(size_t)b * SEQ + i];
    }
    __syncthreads();

    // gather-accumulate in ascending vocab order; thread owns bf16x4 chunk `tid`
    const ushort4* __restrict__ Wb4 = (const ushort4*)Wb;
    float4 acc = make_float4(0.f, 0.f, 0.f, 0.f);
    int p = 0;
    for (; p + PF <= n; p += PF) {
        ushort4 r[PF];
        float   w[PF];
#pragma unroll
        for (int q = 0; q < PF; q++) {
            r[q] = Wb4[(size_t)stoks[p + q] + tid];
            w[q] = wts[p + q];
        }
#pragma unroll
        for (int q = 0; q < PF; q++) {
            acc.x = fmaf(w[q], b2f(r[q].x), acc.x);
            acc.y = fmaf(w[q], b2f(r[q].y), acc.y);
            acc.z = fmaf(w[q], b2f(r[q].z), acc.z);
            acc.w = fmaf(w[q], b2f(r[q].w), acc.w);
        }
    }
    for (; p < n; p++) {
        float w = wts[p];
        ushort4 r = Wb4[(size_t)stoks[p] + tid];
        acc.x = fmaf(w, b2f(r.x), acc.x);
        acc.y = fmaf(w, b2f(r.y), acc.y);
        acc.z = fmaf(w, b2f(r.z), acc.z);
        acc.w = fmaf(w, b2f(r.w), acc.w);
    }

    // L2 norm over 768 dims (intermediate normalize cancels; 1e-10 term ~1e-10 rel)
    float ss = acc.x * acc.x + acc.y * acc.y + acc.z * acc.z + acc.w * acc.w;
#pragma unroll
    for (int off = 32; off > 0; off >>= 1) ss += __shfl_down(ss, off);
    if ((tid & 63) == 0) wred[tid >> 6] = ss;
    __syncthreads();
    float inv = rsqrtf(fmaxf(wred[0] + wred[1] + wred[2], 1e-30f));

    float4 o;
    o.x = acc.x * inv; o.y = acc.y * inv; o.z = acc.z * inv; o.w = acc.w * inv;
    ((float4*)(out + (size_t)b * DMODEL))[tid] = o;
}

extern "C" void kernel_launch(void* const* d_in, const int* in_sizes, int n_in,
                              void* d_out, int out_size, void* d_ws, size_t ws_size,
                              hipStream_t stream) {
    const int*   ids  = (const int*)d_in[0];
    const int*   mask = (const int*)d_in[1];
    const float* W    = (const float*)d_in[2];
    float* out = (float*)d_out;

    char* ws = (char*)d_ws;
    __hip_bfloat16* Wb = (__hip_bfloat16*)ws;               // 46,080,000 B
    size_t off = (size_t)VOC * DMODEL * sizeof(__hip_bfloat16);
    int*   stoks_g = (int*)(ws + off);        off += (size_t)B_ROWS * SEQ * 4;  // 4 MB
    float* wts_g   = (float*)(ws + off);      off += (size_t)B_ROWS * SEQ * 4;  // 4 MB
    int*   n_g     = (int*)(ws + off);

    prep_all<<<TTILES + B_ROWS, 256, 0, stream>>>(W, Wb, ids, mask, stoks_g, wts_g, n_g);

    bm25_gather<<<B_ROWS, NT, 0, stream>>>(stoks_g, wts_g, n_g, Wb, out);
}

// Round 14
// 152.608 us; speedup vs baseline: 1.4701x; 1.0502x over previous
//
#include <hip/hip_runtime.h>
#include <hip/hip_bf16.h>
#include <stdint.h>

#define B_ROWS 2048
#define SEQ 512
#define VOC 30000
#define DMODEL 768
#define K1 1.2f
#define BPAR 0.75f
#define NT 192    // gather: 3 waves; each thread owns one ushort4 (4 bf16) chunk
#define PF 8      // prefetch depth — R7/R13-proven operating point

// ---------------- Kernel 1: per-doc compact + bitonic sort + BM25 weights -------------
// Standalone (4.6 KB LDS -> high occupancy for the barrier-bound sort; R13's fusion
// saddled these blocks with the transpose's 33 KB allocation -> 4 blocks/CU -> 53 us).
// Tokens stored premultiplied by DMODEL/4 (ushort4-row offset).
__launch_bounds__(256)
__global__ void prep_docs(const int* __restrict__ ids, const int* __restrict__ mask,
                          int* __restrict__ stoks_g, float* __restrict__ wts_g,
                          int* __restrict__ n_g) {
    __shared__ int   stoks[SEQ];
    __shared__ float wts[SEQ];
    __shared__ int   nv;

    int b = blockIdx.x;
    int tid = threadIdx.x;

    if (tid == 0) nv = 0;
    __syncthreads();

    // compact valid tokens (order irrelevant; sort follows)
    for (int i = tid; i < SEQ; i += 256) {
        int id = ids[(size_t)b * SEQ + i];
        int m  = mask[(size_t)b * SEQ + i];
        if (m == 1 && id > 100 && id < VOC) {
            stoks[atomicAdd(&nv, 1)] = id;
        }
    }
    __syncthreads();
    int n = nv;   // == doc_len (positions with multiplicity)

    // pad to 512 with +inf keys
    for (int i = n + tid; i < SEQ; i += 256) stoks[i] = 0x7fffffff;

    // bitonic sort of 512 ints (first barrier inside loop covers padding writes)
    for (int k = 2; k <= SEQ; k <<= 1) {
        for (int j = k >> 1; j > 0; j >>= 1) {
            __syncthreads();
            for (int i = tid; i < SEQ; i += 256) {
                int ixj = i ^ j;
                if (ixj > i) {
                    int a = stoks[i], c = stoks[ixj];
                    if ((a > c) == ((i & k) == 0)) { stoks[i] = c; stoks[ixj] = a; }
                }
            }
        }
    }
    __syncthreads();

    // weight: (K1+1)/(tf + K1*len_norm), tf via sorted runs
    float kln = K1 * fmaxf(1.0f + BPAR * ((float)n / 100.0f - 1.0f), 0.5f);
    for (int i = tid; i < n; i += 256) {
        int t = stoks[i];
        int lo = i; while (lo > 0 && stoks[lo - 1] == t) lo--;
        int hi = i; while (hi < n - 1 && stoks[hi + 1] == t) hi++;
        wts[i] = (K1 + 1.0f) / ((float)(hi - lo + 1) + kln);
    }
    __syncthreads();

    // store sorted lists; token premultiplied to ushort4-row offset (tok * DMODEL/4)
    for (int i = tid; i < n; i += 256) {
        stoks_g[(size_t)b * SEQ + i] = stoks[i] * (DMODEL / 4);
        wts_g[(size_t)b * SEQ + i]   = wts[i];
    }
    if (tid == 0) n_g[b] = n;
}

// ---------------- Kernel 2: transpose W [768][30000] f32 -> Wb [30000][768] bf16 -------
// 64j x 256t tiles. Reads: float4 (1KB/wave-instr). Writes: full 128B lines. (R11: ~25us)
__launch_bounds__(256)
__global__ void transpose_W256(const float* __restrict__ W, __hip_bfloat16* __restrict__ Wb) {
    __shared__ __hip_bfloat16 tile[64][258];
    int tBase = blockIdx.x * 256;
    int jBase = blockIdx.y * 64;
    int tx = threadIdx.x;   // 0..63
    int ty = threadIdx.y;   // 0..3

#pragma unroll
    for (int jj = 0; jj < 16; jj++) {
        int j = jBase + jj * 4 + ty;
        int t = tBase + tx * 4;
        if (t < VOC) {   // VOC % 4 == 0 -> full float4 in range
            float4 v = *(const float4*)(W + (size_t)j * VOC + t);
            int c = tx * 4;
            tile[jj * 4 + ty][c]     = __float2bfloat16(v.x);
            tile[jj * 4 + ty][c + 1] = __float2bfloat16(v.y);
            tile[jj * 4 + ty][c + 2] = __float2bfloat16(v.z);
            tile[jj * 4 + ty][c + 3] = __float2bfloat16(v.w);
        }
    }
    __syncthreads();

#pragma unroll
    for (int i = 0; i < 64; i++) {
        int trow = i * 4 + ty;
        int t = tBase + trow;
        if (t < VOC) {
            Wb[(size_t)t * DMODEL + jBase + tx] = tile[tx][trow];
        }
    }
}

__device__ __forceinline__ float b2f(unsigned short h) {
    union { uint32_t u; float f; } v; v.u = ((uint32_t)h) << 16; return v.f;
}

// ---------------- Kernel 3: pure gather + normalize ------------------------------------
// BYTE-IDENTICAL to R13's bm25_gather (107 us, FETCH 326 MB — best proven point).
__launch_bounds__(NT, 6)
__global__ void bm25_gather(const int* __restrict__ stoks_g, const float* __restrict__ wts_g,
                            const int* __restrict__ n_g,
                            const __hip_bfloat16* __restrict__ Wb,
                            float* __restrict__ out) {
    __shared__ int   stoks[SEQ];
    __shared__ float wts[SEQ];
    __shared__ float wred[3];

    int b = blockIdx.x;
    int tid = threadIdx.x;
    int n = n_g[b];   // block-uniform

    for (int i = tid; i < n; i += NT) {
        stoks[i] = stoks_g[(size_t)b * SEQ + i];
        wts[i]   = wts_g[(size_t)b * SEQ + i];
    }
    __syncthreads();

    // gather-accumulate in ascending vocab order; thread owns bf16x4 chunk `tid`
    const ushort4* __restrict__ Wb4 = (const ushort4*)Wb;
    float4 acc = make_float4(0.f, 0.f, 0.f, 0.f);
    int p = 0;
    for (; p + PF <= n; p += PF) {
        ushort4 r[PF];
        float   w[PF];
#pragma unroll
        for (int q = 0; q < PF; q++) {
            r[q] = Wb4[(size_t)stoks[p + q] + tid];
            w[q] = wts[p + q];
        }
#pragma unroll
        for (int q = 0; q < PF; q++) {
            acc.x = fmaf(w[q], b2f(r[q].x), acc.x);
            acc.y = fmaf(w[q], b2f(r[q].y), acc.y);
            acc.z = fmaf(w[q], b2f(r[q].z), acc.z);
            acc.w = fmaf(w[q], b2f(r[q].w), acc.w);
        }
    }
    for (; p < n; p++) {
        float w = wts[p];
        ushort4 r = Wb4[(size_t)stoks[p] + tid];
        acc.x = fmaf(w, b2f(r.x), acc.x);
        acc.y = fmaf(w, b2f(r.y), acc.y);
        acc.z = fmaf(w, b2f(r.z), acc.z);
        acc.w = fmaf(w, b2f(r.w), acc.w);
    }

    // L2 norm over 768 dims (intermediate normalize cancels; 1e-10 term ~1e-10 rel)
    float ss = acc.x * acc.x + acc.y * acc.y + acc.z * acc.z + acc.w * acc.w;
#pragma unroll
    for (int off = 32; off > 0; off >>= 1) ss += __shfl_down(ss, off);
    if ((tid & 63) == 0) wred[tid >> 6] = ss;
    __syncthreads();
    float inv = rsqrtf(fmaxf(wred[0] + wred[1] + wred[2], 1e-30f));

    float4 o;
    o.x = acc.x * inv; o.y = acc.y * inv; o.z = acc.z * inv; o.w = acc.w * inv;
    ((float4*)(out + (size_t)b * DMODEL))[tid] = o;
}

extern "C" void kernel_launch(void* const* d_in, const int* in_sizes, int n_in,
                              void* d_out, int out_size, void* d_ws, size_t ws_size,
                              hipStream_t stream) {
    const int*   ids  = (const int*)d_in[0];
    const int*   mask = (const int*)d_in[1];
    const float* W    = (const float*)d_in[2];
    float* out = (float*)d_out;

    char* ws = (char*)d_ws;
    __hip_bfloat16* Wb = (__hip_bfloat16*)ws;               // 46,080,000 B
    size_t off = (size_t)VOC * DMODEL * sizeof(__hip_bfloat16);
    int*   stoks_g = (int*)(ws + off);        off += (size_t)B_ROWS * SEQ * 4;  // 4 MB
    float* wts_g   = (float*)(ws + off);      off += (size_t)B_ROWS * SEQ * 4;  // 4 MB
    int*   n_g     = (int*)(ws + off);

    prep_docs<<<B_ROWS, 256, 0, stream>>>(ids, mask, stoks_g, wts_g, n_g);

    dim3 tgrid((VOC + 255) / 256, DMODEL / 64);
    dim3 tblock(64, 4);
    transpose_W256<<<tgrid, tblock, 0, stream>>>(W, Wb);

    bm25_gather<<<B_ROWS, NT, 0, stream>>>(stoks_g, wts_g, n_g, Wb, out);
}

// Round 15
// 142.856 us; speedup vs baseline: 1.5705x; 1.0683x over previous
//
#include <hip/hip_runtime.h>
#include <hip/hip_bf16.h>
#include <stdint.h>

#define B_ROWS 2048
#define SEQ 512
#define VOC 30000
#define DMODEL 768
#define K1 1.2f
#define BPAR 0.75f
#define NT 192    // gather: 3 waves; each thread owns one ushort4 (4 bf16) chunk
#define PF 8      // prefetch depth — R7/R13/R14-proven operating point
#define TGX 235   // ceil(VOC/128) transpose tiles in t
#define TGY 12    // DMODEL/64 transpose tiles in j

// ---------------- Kernel 1: fused doc-prep + W-transpose -------------------------------
// Blocks [0, B_ROWS): per-doc compact + bitonic sort + BM25 weights (R14-proven phases).
//   Dispatched FIRST: all 2048 fill the chip (8 blocks/CU wave-cap) for one ~10us round
//   of barrier-bound sorting that uses no memory BW.
// Blocks [B_ROWS, B_ROWS+TGX*TGY): transpose W [768][30000] f32 -> Wb [30000][768] bf16.
//   64j x 128t tiles (LDS 16.6 KB so prep blocks aren't LDS-starved — R13's mistake):
//   float2 512B read segments, full 128B line writes, stride-130 LDS (odd -> no bank
//   conflicts either phase). Overlaps the prep tail -> prelude ~= transpose time alone.
__launch_bounds__(256)
__global__ void prep_trans(const float* __restrict__ W, __hip_bfloat16* __restrict__ Wb,
                           const int* __restrict__ ids, const int* __restrict__ mask,
                           int* __restrict__ stoks_g, float* __restrict__ wts_g,
                           int* __restrict__ n_g) {
    __shared__ ushort smem[64 * 130];   // 16,640 B
    int bid = blockIdx.x;
    int tid = threadIdx.x;

    if (bid < B_ROWS) {
        // ---- doc-prep role ----
        int b = bid;
        int*   stoks = (int*)smem;                    // 512 ints  (2048 B)
        float* wts   = (float*)((char*)smem + 2048);  // 512 f32   (2048 B)
        int*   nvp   = (int*)((char*)smem + 4096);

        if (tid == 0) *nvp = 0;
        __syncthreads();

        for (int i = tid; i < SEQ; i += 256) {
            int id = ids[(size_t)b * SEQ + i];
            int m  = mask[(size_t)b * SEQ + i];
            if (m == 1 && id > 100 && id < VOC) {
                stoks[atomicAdd(nvp, 1)] = id;
            }
        }
        __syncthreads();
        int n = *nvp;   // == doc_len (positions with multiplicity)

        for (int i = n + tid; i < SEQ; i += 256) stoks[i] = 0x7fffffff;

        for (int k = 2; k <= SEQ; k <<= 1) {
            for (int j = k >> 1; j > 0; j >>= 1) {
                __syncthreads();
                for (int i = tid; i < SEQ; i += 256) {
                    int ixj = i ^ j;
                    if (ixj > i) {
                        int a = stoks[i], c = stoks[ixj];
                        if ((a > c) == ((i & k) == 0)) { stoks[i] = c; stoks[ixj] = a; }
                    }
                }
            }
        }
        __syncthreads();

        float kln = K1 * fmaxf(1.0f + BPAR * ((float)n / 100.0f - 1.0f), 0.5f);
        for (int i = tid; i < n; i += 256) {
            int t = stoks[i];
            int lo = i; while (lo > 0 && stoks[lo - 1] == t) lo--;
            int hi = i; while (hi < n - 1 && stoks[hi + 1] == t) hi++;
            wts[i] = (K1 + 1.0f) / ((float)(hi - lo + 1) + kln);
        }
        __syncthreads();

        for (int i = tid; i < n; i += 256) {
            stoks_g[(size_t)b * SEQ + i] = stoks[i] * (DMODEL / 4);  // ushort4-row offset
            wts_g[(size_t)b * SEQ + i]   = wts[i];
        }
        if (tid == 0) n_g[b] = n;
    } else {
        // ---- transpose role ----
        ushort (*tile)[130] = (ushort(*)[130])smem;   // [j_local][t_local]
        int tb = bid - B_ROWS;
        int bx = tb % TGX, by = tb / TGX;
        int tBase = bx * 128;
        int jBase = by * 64;
        int tx = tid & 63;    // lane
        int ty = tid >> 6;    // wave

        // read: wave ty reads j-rows jBase + jj*4 + ty; lane covers 2 cols (float2, 512B)
#pragma unroll
        for (int jj = 0; jj < 16; jj++) {
            int j = jBase + jj * 4 + ty;
            int t = tBase + tx * 2;
            if (t < VOC) {   // VOC even -> full float2 in range
                float2 v = *(const float2*)(W + (size_t)j * VOC + t);
                ushort2 u;
                u.x = __bfloat16_as_ushort(__float2bfloat16(v.x));
                u.y = __bfloat16_as_ushort(__float2bfloat16(v.y));
                *(ushort2*)&tile[jj * 4 + ty][tx * 2] = u;
            }
        }
        __syncthreads();

        // write: wave ty writes t-rows i*4 + ty; 64 lanes x 2B = one full 128B line
#pragma unroll
        for (int i = 0; i < 32; i++) {
            int trow = i * 4 + ty;
            int t = tBase + trow;
            if (t < VOC) {
                ((ushort*)Wb)[(size_t)t * DMODEL + jBase + tx] = tile[tx][trow];
            }
        }
    }
}

__device__ __forceinline__ float b2f(unsigned short h) {
    union { uint32_t u; float f; } v; v.u = ((uint32_t)h) << 16; return v.f;
}

// ---------------- Kernel 2: pure gather + normalize ------------------------------------
// BYTE-IDENTICAL to R13/R14's bm25_gather (107 us, FETCH 326 MB — proven 3x).
__launch_bounds__(NT, 6)
__global__ void bm25_gather(const int* __restrict__ stoks_g, const float* __restrict__ wts_g,
                            const int* __restrict__ n_g,
                            const __hip_bfloat16* __restrict__ Wb,
                            float* __restrict__ out) {
    __shared__ int   stoks[SEQ];
    __shared__ float wts[SEQ];
    __shared__ float wred[3];

    int b = blockIdx.x;
    int tid = threadIdx.x;
    int n = n_g[b];   // block-uniform

    for (int i = tid; i < n; i += NT) {
        stoks[i] = stoks_g[(size_t)b * SEQ + i];
        wts[i]   = wts_g[(size_t)b * SEQ + i];
    }
    __syncthreads();

    // gather-accumulate in ascending vocab order; thread owns bf16x4 chunk `tid`
    const ushort4* __restrict__ Wb4 = (const ushort4*)Wb;
    float4 acc = make_float4(0.f, 0.f, 0.f, 0.f);
    int p = 0;
    for (; p + PF <= n; p += PF) {
        ushort4 r[PF];
        float   w[PF];
#pragma unroll
        for (int q = 0; q < PF; q++) {
            r[q] = Wb4[(size_t)stoks[p + q] + tid];
            w[q] = wts[p + q];
        }
#pragma unroll
        for (int q = 0; q < PF; q++) {
            acc.x = fmaf(w[q], b2f(r[q].x), acc.x);
            acc.y = fmaf(w[q], b2f(r[q].y), acc.y);
            acc.z = fmaf(w[q], b2f(r[q].z), acc.z);
            acc.w = fmaf(w[q], b2f(r[q].w), acc.w);
        }
    }
    for (; p < n; p++) {
        float w = wts[p];
        ushort4 r = Wb4[(size_t)stoks[p] + tid];
        acc.x = fmaf(w, b2f(r.x), acc.x);
        acc.y = fmaf(w, b2f(r.y), acc.y);
        acc.z = fmaf(w, b2f(r.z), acc.z);
        acc.w = fmaf(w, b2f(r.w), acc.w);
    }

    // L2 norm over 768 dims (intermediate normalize cancels; 1e-10 term ~1e-10 rel)
    float ss = acc.x * acc.x + acc.y * acc.y + acc.z * acc.z + acc.w * acc.w;
#pragma unroll
    for (int off = 32; off > 0; off >>= 1) ss += __shfl_down(ss, off);
    if ((tid & 63) == 0) wred[tid >> 6] = ss;
    __syncthreads();
    float inv = rsqrtf(fmaxf(wred[0] + wred[1] + wred[2], 1e-30f));

    float4 o;
    o.x = acc.x * inv; o.y = acc.y * inv; o.z = acc.z * inv; o.w = acc.w * inv;
    ((float4*)(out + (size_t)b * DMODEL))[tid] = o;
}

extern "C" void kernel_launch(void* const* d_in, const int* in_sizes, int n_in,
                              void* d_out, int out_size, void* d_ws, size_t ws_size,
                              hipStream_t stream) {
    const int*   ids  = (const int*)d_in[0];
    const int*   mask = (const int*)d_in[1];
    const float* W    = (const float*)d_in[2];
    float* out = (float*)d_out;

    char* ws = (char*)d_ws;
    __hip_bfloat16* Wb = (__hip_bfloat16*)ws;               // 46,080,000 B
    size_t off = (size_t)VOC * DMODEL * sizeof(__hip_bfloat16);
    int*   stoks_g = (int*)(ws + off);        off += (size_t)B_ROWS * SEQ * 4;  // 4 MB
    float* wts_g   = (float*)(ws + off);      off += (size_t)B_ROWS * SEQ * 4;  // 4 MB
    int*   n_g     = (int*)(ws + off);

    prep_trans<<<B_ROWS + TGX * TGY, 256, 0, stream>>>(W, Wb, ids, mask,
                                                       stoks_g, wts_g, n_g);

    bm25_gather<<<B_ROWS, NT, 0, stream>>>(stoks_g, wts_g, n_g, Wb, out);
}